// Round 6
// baseline (8355.331 us; speedup 1.0000x reference)
//
#include <hip/hip_runtime.h>
#include <hip/hip_bf16.h>
#include <hip/hip_fp16.h>

// Non-local means, 8x3x512x512 fp32, search 21x21 (R=10), patch 7x7 (PR=3),
// circular wrap (jnp.roll semantics).
//
// v3: conflict-free split-row pixel layout (R|G at col, B|Y at col+91 within a
// 183-word row -> lane stride 1 word, 2-way max); ys_full[37] register column
// per dx with dy fully unrolled (no slide movs, all static indexing).

#define IMG   512
#define HW    (IMG*IMG)
#define TW    64
#define TH    32
#define RWIN  10
#define HALO  13              // RWIN + PR
#define PROWS 59              // staged rows 0..58
#define PCOLS 91              // staged cols 0..90
#define PSTR  183             // words per staged row: [0,90]=R|G  [91,181]=B|Y  182 pad
#define VSTR  71              // vert: 70 cols (-3..66) + 1 pad, odd
#define VROWS 33              // 32 + 1 junk row from strip rg=2

__device__ __forceinline__ uint32_t f2bf(float x) {   // f32 -> bf16 bits (RNE)
    uint32_t u = __float_as_uint(x);
    return (u + 0x7fffu + ((u >> 16) & 1u)) >> 16;
}

// Y (fp16) lives in hi16 of the B|Y word (word col+91)
#define LDY(row, col) \
    __half2float(((const __half*)pixw)[((((row)*PSTR + 91 + (col))) << 1) | 1])

__launch_bounds__(256, 3)
__global__ void nlm_kernel(const float* __restrict__ rgb,
                           const float* __restrict__ hptr,
                           float* __restrict__ out)
{
    __shared__ uint32_t pixw[PROWS * PSTR];   // 43188 B
    __shared__ float    vert[VROWS * VSTR];   //  9372 B   (total 52560 B -> 3 blk/CU)

    const int tid = threadIdx.x;
    const int tx  = blockIdx.x;   // 0..7
    const int ty  = blockIdx.y;   // 0..15
    const int b   = blockIdx.z;   // 0..7

    const float hval  = hptr[0];
    const float inv_h = 1.0f / (fmaxf(hval, 0.0f) + 1e-8f);
    const float sc    = -inv_h * 1.4426950408889634f;   // exp2 scale

    // ---------------- stage packed RGBY ------------------------------------
    const size_t ibase = (size_t)b * 3 * HW;
    const int row0 = ty*TH - HALO;
    const int col0 = tx*TW - HALO;
    for (int i = tid; i < PROWS*PCOLS; i += 256) {
        int rr = i / PCOLS;
        int cc = i - rr*PCOLS;
        int gr = (row0 + rr) & (IMG-1);
        int gc = (col0 + cc) & (IMG-1);
        size_t g = ibase + (size_t)gr*IMG + gc;
        float R  = fminf(fmaxf(rgb[g         ], 0.f), 1.f);
        float G  = fminf(fmaxf(rgb[g +     HW], 0.f), 1.f);
        float Bv = fminf(fmaxf(rgb[g + 2 * HW], 0.f), 1.f);
        float Y  = 0.299f*R + 0.587f*G + 0.114f*Bv;
        int o = rr*PSTR + cc;
        pixw[o     ] = f2bf(R) | (f2bf(G) << 16);
        pixw[o + 91] = f2bf(Bv) | ((uint32_t)__half_as_ushort(__float2half(Y)) << 16);
    }
    __syncthreads();

    // ---------------- phase-1 statics: 210 column strips --------------------
    const int  c  = tid % 70;         // vert col slot (abs tile col c-3)
    const int  rg = tid / 70;         // 0..2
    const int  r0 = rg * 11;          // vert rows r0..r0+10 (rg=2 row 32 junk)
    const bool p1 = tid < 210;
    float yown[17];
    if (p1) {
        #pragma unroll
        for (int k = 0; k < 17; ++k)
            yown[k] = LDY(r0 + 10 + k, c + 10);     // tile rows r0-3..r0+13
    }

    // ---------------- phase-2 statics ---------------------------------------
    const int r   = tid >> 3;         // 0..31
    const int c0  = (tid & 7) * 8;    // 0..56
    const int vb2 = r*VSTR + c0;      // vp[0..13] = vert cols c0-3..c0+10

    float aR[8], aG[8], aB[8], aD[8];
    #pragma unroll
    for (int j = 0; j < 8; ++j) { aR[j]=0.f; aG[j]=0.f; aB[j]=0.f; aD[j]=0.f; }

    // ---------------- shift loop: dx outer, dy fully unrolled ---------------
    #pragma unroll 1
    for (int dx = -RWIN; dx <= RWIN; ++dx) {
        const int cs = c + 10 - dx;               // shifted y column (0..89)
        float ys_full[37];                        // ys_full[m] = Y(r0+m, cs)
        if (p1) {
            #pragma unroll
            for (int m = 0; m < 37; ++m)
                ys_full[m] = LDY(r0 + m, cs);
        }
        #pragma unroll
        for (int dy = -RWIN; dy <= RWIN; ++dy) {
            // ---- phase 1: vertical 7-box of (y - y_shifted)^2 ----
            if (p1) {
                float d[17];
                #pragma unroll
                for (int k = 0; k < 17; ++k) {
                    float t = yown[k] - ys_full[10 + k - dy];
                    d[k] = t*t;
                }
                float v = d[0]+d[1]+d[2]+d[3]+d[4]+d[5]+d[6];
                int vb = r0*VSTR + c;
                vert[vb] = v;
                #pragma unroll
                for (int j = 1; j < 11; ++j) {
                    v += d[j+6] - d[j-1];
                    vert[vb + j*VSTR] = v;
                }
            }
            __syncthreads();
            // ---- phase 2: horizontal 7-slide + weight + accumulate ----
            {
                const float* vp = &vert[vb2];
                float hacc = vp[0]+vp[1]+vp[2]+vp[3]+vp[4]+vp[5]+vp[6];
                const int prow = r - dy + HALO;           // 3..54
                const int pb   = prow*PSTR + (c0 - dx + HALO);
                #pragma unroll
                for (int j = 0; j < 8; ++j) {
                    if (j) hacc += vp[j+6] - vp[j-1];
                    float dist = __builtin_amdgcn_sqrtf(fmaxf(hacc, 0.0f));
                    float w    = __builtin_amdgcn_exp2f(dist * sc);
                    uint32_t w0 = pixw[pb + j     ];      // R|G
                    uint32_t w1 = pixw[pb + j + 91];      // B|Y
                    float R  = __uint_as_float(w0 << 16);
                    float G  = __uint_as_float(w0 & 0xffff0000u);
                    float Bv = __uint_as_float(w1 << 16);
                    aR[j] += w * R;
                    aG[j] += w * G;
                    aB[j] += w * Bv;
                    aD[j] += w;
                }
            }
            __syncthreads();
        }
    }

    // ---------------- epilogue ----------------------------------------------
    const int gr = ty*TH + r;
    const int gc = tx*TW + c0;
    float* op = out + ibase + (size_t)gr*IMG + gc;
    #pragma unroll
    for (int j = 0; j < 8; ++j) {
        float iv = 1.0f / aD[j];
        op[j         ] = fminf(fmaxf(aR[j]*iv, 0.f), 1.f);
        op[j +     HW] = fminf(fmaxf(aG[j]*iv, 0.f), 1.f);
        op[j + 2 * HW] = fminf(fmaxf(aB[j]*iv, 0.f), 1.f);
    }
}

extern "C" void kernel_launch(void* const* d_in, const int* in_sizes, int n_in,
                              void* d_out, int out_size, void* d_ws, size_t ws_size,
                              hipStream_t stream) {
    const float* rgb = (const float*)d_in[0];
    const float* h   = (const float*)d_in[1];
    float* out       = (float*)d_out;
    dim3 grid(IMG/TW, IMG/TH, 8);   // 8 x 16 x 8 = 1024 blocks
    nlm_kernel<<<grid, 256, 0, stream>>>(rgb, h, out);
}

// Round 7
// 977.650 us; speedup vs baseline: 8.5463x; 8.5463x over previous
//
#include <hip/hip_runtime.h>
#include <hip/hip_bf16.h>
#include <hip/hip_fp16.h>

// Non-local means, 8x3x512x512 fp32, search 21x21 (R=10), patch 7x7 (PR=3),
// circular wrap (jnp.roll semantics).
//
// v4 = v2 control structure (dy-inner, sliding ys[17] register window, unroll 3
//      -> no spills, 84 VGPR) + v3 split-row conflict-free LDS layout
//      (R|G at row*183+col, B|Y at row*183+91+col -> lane word-stride 1,
//       2-way banking = free; was 4-way in v2 = 2.4e8 conflict cycles).

#define IMG   512
#define HW    (IMG*IMG)
#define TW    64
#define TH    32
#define RWIN  10
#define HALO  13              // RWIN + PR
#define PROWS 59              // staged rows 0..58
#define PCOLS 91              // staged cols 0..90
#define PSTR  183             // words/row: [0,90]=R|G  [91,181]=B|Y  [182] pad
#define VSTR  71              // vert: 70 cols (-3..66) + 1 pad, odd
#define VROWS 33              // 32 + 1 junk row from strip rg=2

__device__ __forceinline__ uint32_t f2bf(float x) {   // f32 -> bf16 bits (RNE)
    uint32_t u = __float_as_uint(x);
    return (u + 0x7fffu + ((u >> 16) & 1u)) >> 16;
}

// Y (fp16) lives in hi16 of the B|Y word (word col+91)
#define LDY(row, col) \
    __half2float(((const __half*)pixw)[((((row)*PSTR + 91 + (col))) << 1) | 1])

__launch_bounds__(256, 3)
__global__ void nlm_kernel(const float* __restrict__ rgb,
                           const float* __restrict__ hptr,
                           float* __restrict__ out)
{
    __shared__ uint32_t pixw[PROWS * PSTR];   // 43188 B
    __shared__ float    vert[VROWS * VSTR];   //  9372 B  (52560 B -> 3 blk/CU)

    const int tid = threadIdx.x;
    const int tx  = blockIdx.x;   // 0..7
    const int ty  = blockIdx.y;   // 0..15
    const int b   = blockIdx.z;   // 0..7

    const float hval  = hptr[0];
    const float inv_h = 1.0f / (fmaxf(hval, 0.0f) + 1e-8f);
    const float sc    = -inv_h * 1.4426950408889634f;   // exp2 scale

    // ---------------- stage packed RGBY ------------------------------------
    const size_t ibase = (size_t)b * 3 * HW;
    const int row0 = ty*TH - HALO;
    const int col0 = tx*TW - HALO;
    for (int i = tid; i < PROWS*PCOLS; i += 256) {
        int rr = i / PCOLS;
        int cc = i - rr*PCOLS;
        int gr = (row0 + rr) & (IMG-1);
        int gc = (col0 + cc) & (IMG-1);
        size_t g = ibase + (size_t)gr*IMG + gc;
        float R  = fminf(fmaxf(rgb[g         ], 0.f), 1.f);
        float G  = fminf(fmaxf(rgb[g +     HW], 0.f), 1.f);
        float Bv = fminf(fmaxf(rgb[g + 2 * HW], 0.f), 1.f);
        float Y  = 0.299f*R + 0.587f*G + 0.114f*Bv;
        int o = rr*PSTR + cc;
        pixw[o     ] = f2bf(R) | (f2bf(G) << 16);
        pixw[o + 91] = f2bf(Bv) | ((uint32_t)__half_as_ushort(__float2half(Y)) << 16);
    }
    __syncthreads();

    // ---------------- phase-1 statics: 210 column strips --------------------
    const int  c  = tid % 70;         // vert col slot (abs tile col c-3)
    const int  rg = tid / 70;         // 0..2
    const int  r0 = rg * 11;          // vert rows r0..r0+10 (rg=2 row 32 junk)
    const bool p1 = tid < 210;
    float yown[17];
    if (p1) {
        #pragma unroll
        for (int k = 0; k < 17; ++k)
            yown[k] = LDY(r0 + 10 + k, c + 10);     // tile rows r0-3..r0+13
    }

    // ---------------- phase-2 statics ---------------------------------------
    const int r   = tid >> 3;         // 0..31
    const int c0  = (tid & 7) * 8;    // 0..56
    const int vb2 = r*VSTR + c0;      // vp[0..13] = vert cols c0-3..c0+10

    float aR[8], aG[8], aB[8], aD[8];
    #pragma unroll
    for (int j = 0; j < 8; ++j) { aR[j]=0.f; aG[j]=0.f; aB[j]=0.f; aD[j]=0.f; }

    // ---------------- shift loop: dx outer, dy inner (sliding window) -------
    #pragma unroll 1
    for (int dx = -RWIN; dx <= RWIN; ++dx) {
        const int cs = c + 10 - dx;               // shifted y column (0..89)
        float ys[17];                             // ys[k] = Y[r0+10+k-dy]
        if (p1) {
            #pragma unroll
            for (int k = 0; k < 17; ++k)
                ys[k] = LDY(r0 + 20 + k, cs);     // fill for dy=-10
        }
        #pragma unroll 3
        for (int dy = -RWIN; dy <= RWIN; ++dy) {
            // ---- phase 1: vertical 7-box of (y - y_shifted)^2 ----
            if (p1) {
                float d[17];
                #pragma unroll
                for (int k = 0; k < 17; ++k) {
                    float t = yown[k] - ys[k];
                    d[k] = t*t;
                }
                float v = d[0]+d[1]+d[2]+d[3]+d[4]+d[5]+d[6];
                int vb = r0*VSTR + c;
                vert[vb] = v;
                #pragma unroll
                for (int j = 1; j < 11; ++j) {
                    v += d[j+6] - d[j-1];
                    vert[vb + j*VSTR] = v;
                }
            }
            __syncthreads();
            // ---- phase 2: horizontal 7-slide + weight + accumulate ----
            {
                const float* vp = &vert[vb2];
                float hacc = vp[0]+vp[1]+vp[2]+vp[3]+vp[4]+vp[5]+vp[6];
                const int prow = r - dy + HALO;           // 3..54
                const int pb   = prow*PSTR + (c0 - dx + HALO);
                #pragma unroll
                for (int j = 0; j < 8; ++j) {
                    if (j) hacc += vp[j+6] - vp[j-1];
                    float dist = __builtin_amdgcn_sqrtf(fmaxf(hacc, 0.0f));
                    float w    = __builtin_amdgcn_exp2f(dist * sc);
                    uint32_t w0 = pixw[pb + j     ];      // R|G
                    uint32_t w1 = pixw[pb + j + 91];      // B|Y
                    float R  = __uint_as_float(w0 << 16);
                    float G  = __uint_as_float(w0 & 0xffff0000u);
                    float Bv = __uint_as_float(w1 << 16);
                    aR[j] += w * R;
                    aG[j] += w * G;
                    aB[j] += w * Bv;
                    aD[j] += w;
                }
            }
            __syncthreads();
            // ---- slide shifted-y window down one row for next dy ----
            if (p1 && dy < RWIN) {
                #pragma unroll
                for (int k = 16; k >= 1; --k) ys[k] = ys[k-1];
                ys[0] = LDY(r0 + 9 - dy, cs);
            }
        }
    }

    // ---------------- epilogue ----------------------------------------------
    const int gr = ty*TH + r;
    const int gc = tx*TW + c0;
    float* op = out + ibase + (size_t)gr*IMG + gc;
    #pragma unroll
    for (int j = 0; j < 8; ++j) {
        float iv = 1.0f / aD[j];
        op[j         ] = fminf(fmaxf(aR[j]*iv, 0.f), 1.f);
        op[j +     HW] = fminf(fmaxf(aG[j]*iv, 0.f), 1.f);
        op[j + 2 * HW] = fminf(fmaxf(aB[j]*iv, 0.f), 1.f);
    }
}

extern "C" void kernel_launch(void* const* d_in, const int* in_sizes, int n_in,
                              void* d_out, int out_size, void* d_ws, size_t ws_size,
                              hipStream_t stream) {
    const float* rgb = (const float*)d_in[0];
    const float* h   = (const float*)d_in[1];
    float* out       = (float*)d_out;
    dim3 grid(IMG/TW, IMG/TH, 8);   // 8 x 16 x 8 = 1024 blocks
    nlm_kernel<<<grid, 256, 0, stream>>>(rgb, h, out);
}

// Round 8
// 853.667 us; speedup vs baseline: 9.7876x; 1.1452x over previous
//
#include <hip/hip_runtime.h>
#include <hip/hip_bf16.h>
#include <hip/hip_fp16.h>

// Non-local means, 8x3x512x512 fp32, search 21x21 (R=10), patch 7x7 (PR=3),
// circular wrap (jnp.roll semantics).
//
// v5 = v4 + vert transposed [col][row] stride 33:
//   phase-1 writes are 11 consecutive words (write2/b64-pairable, 2-way banks);
//   phase-2 reads fold into one base + imm offsets (zero addr VALU, read2-
//   mergeable), banks (8cg+r+k') mod 32 = exact 2/bank (free).
// LDS 52428 B -> 3 blocks/CU.

#define IMG   512
#define HW    (IMG*IMG)
#define TW    64
#define TH    32
#define RWIN  10
#define HALO  13              // RWIN + PR
#define PROWS 59              // staged rows 0..58
#define PCOLS 91              // staged cols 0..90
#define PSTR  183             // words/row: [0,90]=R|G  [91,181]=B|Y  [182] pad
#define VTSTR 33              // vert_t: [col 0..69][row 0..32], stride 33

__device__ __forceinline__ uint32_t f2bf(float x) {   // f32 -> bf16 bits (RNE)
    uint32_t u = __float_as_uint(x);
    return (u + 0x7fffu + ((u >> 16) & 1u)) >> 16;
}

// Y (fp16) lives in hi16 of the B|Y word (word col+91)
#define LDY(row, col) \
    __half2float(((const __half*)pixw)[((((row)*PSTR + 91 + (col))) << 1) | 1])

__launch_bounds__(256, 3)
__global__ void nlm_kernel(const float* __restrict__ rgb,
                           const float* __restrict__ hptr,
                           float* __restrict__ out)
{
    __shared__ uint32_t pixw[PROWS * PSTR];    // 43188 B
    __shared__ float    vert_t[70 * VTSTR];    //  9240 B  (52428 B -> 3 blk/CU)

    const int tid = threadIdx.x;
    const int tx  = blockIdx.x;   // 0..7
    const int ty  = blockIdx.y;   // 0..15
    const int b   = blockIdx.z;   // 0..7

    const float hval  = hptr[0];
    const float inv_h = 1.0f / (fmaxf(hval, 0.0f) + 1e-8f);
    const float sc    = -inv_h * 1.4426950408889634f;   // exp2 scale

    // ---------------- stage packed RGBY ------------------------------------
    const size_t ibase = (size_t)b * 3 * HW;
    const int row0 = ty*TH - HALO;
    const int col0 = tx*TW - HALO;
    for (int i = tid; i < PROWS*PCOLS; i += 256) {
        int rr = i / PCOLS;
        int cc = i - rr*PCOLS;
        int gr = (row0 + rr) & (IMG-1);
        int gc = (col0 + cc) & (IMG-1);
        size_t g = ibase + (size_t)gr*IMG + gc;
        float R  = fminf(fmaxf(rgb[g         ], 0.f), 1.f);
        float G  = fminf(fmaxf(rgb[g +     HW], 0.f), 1.f);
        float Bv = fminf(fmaxf(rgb[g + 2 * HW], 0.f), 1.f);
        float Y  = 0.299f*R + 0.587f*G + 0.114f*Bv;
        int o = rr*PSTR + cc;
        pixw[o     ] = f2bf(R) | (f2bf(G) << 16);
        pixw[o + 91] = f2bf(Bv) | ((uint32_t)__half_as_ushort(__float2half(Y)) << 16);
    }
    __syncthreads();

    // ---------------- phase-1 statics: 210 column strips --------------------
    const int  c  = tid % 70;         // vert col slot (tile col c-3)
    const int  rg = tid / 70;         // 0..2
    const int  r0 = rg * 11;          // vert rows r0..r0+10 (rg=2 row 32 junk)
    const bool p1 = tid < 210;
    float yown[17];
    if (p1) {
        #pragma unroll
        for (int k = 0; k < 17; ++k)
            yown[k] = LDY(r0 + 10 + k, c + 10);     // tile rows r0-3..r0+13
    }

    // ---------------- phase-2 statics ---------------------------------------
    const int r   = tid >> 3;         // 0..31
    const int c0  = (tid & 7) * 8;    // 0..56
    // vp[k'] = vert_t[(c0+k')*VTSTR + r], k'=0..13  (tile cols c0-3..c0+10)
    const int vb2 = c0*VTSTR + r;

    float aR[8], aG[8], aB[8], aD[8];
    #pragma unroll
    for (int j = 0; j < 8; ++j) { aR[j]=0.f; aG[j]=0.f; aB[j]=0.f; aD[j]=0.f; }

    // ---------------- shift loop: dx outer, dy inner (sliding window) -------
    #pragma unroll 1
    for (int dx = -RWIN; dx <= RWIN; ++dx) {
        const int cs = c + 10 - dx;               // shifted y column (0..89)
        float ys[17];                             // ys[k] = Y[r0+10+k-dy]
        if (p1) {
            #pragma unroll
            for (int k = 0; k < 17; ++k)
                ys[k] = LDY(r0 + 20 + k, cs);     // fill for dy=-10
        }
        #pragma unroll 3
        for (int dy = -RWIN; dy <= RWIN; ++dy) {
            // ---- phase 1: vertical 7-box of (y - y_shifted)^2 ----
            if (p1) {
                float d[17];
                #pragma unroll
                for (int k = 0; k < 17; ++k) {
                    float t = yown[k] - ys[k];
                    d[k] = t*t;
                }
                float v = d[0]+d[1]+d[2]+d[3]+d[4]+d[5]+d[6];
                float* vp = &vert_t[c*VTSTR + r0];   // 11 consecutive words
                vp[0] = v;
                #pragma unroll
                for (int j = 1; j < 11; ++j) {
                    v += d[j+6] - d[j-1];
                    vp[j] = v;
                }
            }
            __syncthreads();
            // ---- phase 2: horizontal 7-slide + weight + accumulate ----
            {
                const float* vp = &vert_t[vb2];
                float vv[14];
                #pragma unroll
                for (int k = 0; k < 14; ++k) vv[k] = vp[k*VTSTR];
                float hacc = vv[0]+vv[1]+vv[2]+vv[3]+vv[4]+vv[5]+vv[6];
                const int prow = r - dy + HALO;           // 3..54
                const int pb   = prow*PSTR + (c0 - dx + HALO);
                #pragma unroll
                for (int j = 0; j < 8; ++j) {
                    if (j) hacc += vv[j+6] - vv[j-1];
                    float dist = __builtin_amdgcn_sqrtf(fmaxf(hacc, 0.0f));
                    float w    = __builtin_amdgcn_exp2f(dist * sc);
                    uint32_t w0 = pixw[pb + j     ];      // R|G
                    uint32_t w1 = pixw[pb + j + 91];      // B|Y
                    float R  = __uint_as_float(w0 << 16);
                    float G  = __uint_as_float(w0 & 0xffff0000u);
                    float Bv = __uint_as_float(w1 << 16);
                    aR[j] += w * R;
                    aG[j] += w * G;
                    aB[j] += w * Bv;
                    aD[j] += w;
                }
            }
            __syncthreads();
            // ---- slide shifted-y window down one row for next dy ----
            if (p1 && dy < RWIN) {
                #pragma unroll
                for (int k = 16; k >= 1; --k) ys[k] = ys[k-1];
                ys[0] = LDY(r0 + 9 - dy, cs);
            }
        }
    }

    // ---------------- epilogue ----------------------------------------------
    const int gr = ty*TH + r;
    const int gc = tx*TW + c0;
    float* op = out + ibase + (size_t)gr*IMG + gc;
    #pragma unroll
    for (int j = 0; j < 8; ++j) {
        float iv = 1.0f / aD[j];
        op[j         ] = fminf(fmaxf(aR[j]*iv, 0.f), 1.f);
        op[j +     HW] = fminf(fmaxf(aG[j]*iv, 0.f), 1.f);
        op[j + 2 * HW] = fminf(fmaxf(aB[j]*iv, 0.f), 1.f);
    }
}

extern "C" void kernel_launch(void* const* d_in, const int* in_sizes, int n_in,
                              void* d_out, int out_size, void* d_ws, size_t ws_size,
                              hipStream_t stream) {
    const float* rgb = (const float*)d_in[0];
    const float* h   = (const float*)d_in[1];
    float* out       = (float*)d_out;
    dim3 grid(IMG/TW, IMG/TH, 8);   // 8 x 16 x 8 = 1024 blocks
    nlm_kernel<<<grid, 256, 0, stream>>>(rgb, h, out);
}

// Round 9
// 820.680 us; speedup vs baseline: 10.1810x; 1.0402x over previous
//
#include <hip/hip_runtime.h>
#include <hip/hip_fp16.h>

// Non-local means, 8x3x512x512 fp32, search 21x21 (R=10), patch 7x7 (PR=3),
// circular wrap (jnp.roll semantics).
//
// v6 = v5 + VALU-instr cut package:
//   - f16 pixel storage (half2 R|G, B|Y) + "acc += w*(float)h" fma_mix pattern
//     (kills unpack bit-ops; f16->f32 is exact)
//   - ys[19] window slides by 3 dy per rotation (16 movs / 3 dy instead of /1),
//     inner 3 iterations unrolled -> all register indices static (no v3 spill)
//   - phase-1 difference-of-squares fma form (54 ops vs 60)

#define IMG   512
#define HW    (IMG*IMG)
#define TW    64
#define TH    32
#define RWIN  10
#define HALO  13              // RWIN + PR
#define PROWS 59              // staged rows 0..58
#define PCOLS 91              // staged cols 0..90
#define PSTR  183             // half2 words/row: [0,90]=R|G  [91,181]=B|Y  [182] pad
#define VTSTR 33              // vert_t: [col 0..69][row 0..32]

// Y (f16) is the hi half (.y) of the B|Y word
#define LDY(row, col) __half2float(pixh2[(row)*PSTR + 91 + (col)].y)

__launch_bounds__(256, 3)
__global__ void nlm_kernel(const float* __restrict__ rgb,
                           const float* __restrict__ hptr,
                           float* __restrict__ out)
{
    __shared__ __half2 pixh2[PROWS * PSTR];    // 43188 B
    __shared__ float   vert_t[70 * VTSTR];     //  9240 B  (52428 B -> 3 blk/CU)

    const int tid = threadIdx.x;
    const int tx  = blockIdx.x;   // 0..7
    const int ty  = blockIdx.y;   // 0..15
    const int b   = blockIdx.z;   // 0..7

    const float hval  = hptr[0];
    const float inv_h = 1.0f / (fmaxf(hval, 0.0f) + 1e-8f);
    const float sc    = -inv_h * 1.4426950408889634f;   // exp2 scale

    // ---------------- stage packed RGBY (f16) -------------------------------
    const size_t ibase = (size_t)b * 3 * HW;
    const int row0 = ty*TH - HALO;
    const int col0 = tx*TW - HALO;
    for (int i = tid; i < PROWS*PCOLS; i += 256) {
        int rr = i / PCOLS;
        int cc = i - rr*PCOLS;
        int gr = (row0 + rr) & (IMG-1);
        int gc = (col0 + cc) & (IMG-1);
        size_t g = ibase + (size_t)gr*IMG + gc;
        float R  = fminf(fmaxf(rgb[g         ], 0.f), 1.f);
        float G  = fminf(fmaxf(rgb[g +     HW], 0.f), 1.f);
        float Bv = fminf(fmaxf(rgb[g + 2 * HW], 0.f), 1.f);
        float Y  = 0.299f*R + 0.587f*G + 0.114f*Bv;
        int o = rr*PSTR + cc;
        pixh2[o     ] = __floats2half2_rn(R, G);
        pixh2[o + 91] = __floats2half2_rn(Bv, Y);
    }
    __syncthreads();

    // ---------------- phase-1 statics: 210 column strips --------------------
    const int  c  = tid % 70;         // vert col slot (tile col c-3)
    const int  rg = tid / 70;         // 0..2
    const int  r0 = rg * 11;          // vert rows r0..r0+10 (rg=2 row 32 junk)
    const bool p1 = tid < 210;
    float yown[17];
    if (p1) {
        #pragma unroll
        for (int k = 0; k < 17; ++k)
            yown[k] = LDY(r0 + 10 + k, c + 10);     // staged rows r0+7..r0+23
    }

    // ---------------- phase-2 statics ---------------------------------------
    const int r   = tid >> 3;         // 0..31
    const int c0  = (tid & 7) * 8;    // 0..56
    const int vb2 = c0*VTSTR + r;     // vv[k] = vert_t[(c0+k)*VTSTR + r]

    float aR[8], aG[8], aB[8], aD[8];
    #pragma unroll
    for (int j = 0; j < 8; ++j) { aR[j]=0.f; aG[j]=0.f; aB[j]=0.f; aD[j]=0.f; }

    // ---------------- shift loop: dx outer, dy in groups of 3 ---------------
    #pragma unroll 1
    for (int dx = -RWIN; dx <= RWIN; ++dx) {
        const int cs = c + 10 - dx;               // shifted y column (0..89)
        // ys[m] = Y(r0 + 10 + (m-2) - d, cs) for current group base d
        float ys[19];
        if (p1) {
            #pragma unroll
            for (int m = 0; m < 19; ++m)
                ys[m] = LDY(r0 + 18 + m, cs);     // fill for d = -10
        }
        #pragma unroll 1
        for (int g = 0; g < 7; ++g) {
            const int d = -RWIN + 3*g;
            #pragma unroll
            for (int i = 0; i < 3; ++i) {
                const int dy = d + i;
                // ---- phase 1: vertical 7-box of (y - y_shifted)^2 ----
                if (p1) {
                    float t[17];
                    #pragma unroll
                    for (int k = 0; k < 17; ++k)
                        t[k] = yown[k] - ys[k + 2 - i];   // static index
                    float v = t[0]*t[0];
                    #pragma unroll
                    for (int k = 1; k < 7; ++k) v = fmaf(t[k], t[k], v);
                    float* vp = &vert_t[c*VTSTR + r0];    // 11 consecutive words
                    vp[0] = v;
                    #pragma unroll
                    for (int j = 1; j < 11; ++j) {
                        v = fmaf(t[j+6]-t[j-1], t[j+6]+t[j-1], v);
                        vp[j] = v;
                    }
                }
                __syncthreads();
                // ---- phase 2: horizontal 7-slide + weight + accumulate ----
                {
                    const float* vp = &vert_t[vb2];
                    float vv[14];
                    #pragma unroll
                    for (int k = 0; k < 14; ++k) vv[k] = vp[k*VTSTR];
                    float hacc = vv[0]+vv[1]+vv[2]+vv[3]+vv[4]+vv[5]+vv[6];
                    const int prow = r - dy + HALO;       // 3..54
                    const int pb   = prow*PSTR + (c0 - dx + HALO);
                    #pragma unroll
                    for (int j = 0; j < 8; ++j) {
                        if (j) hacc += vv[j+6] - vv[j-1];
                        float dist = __builtin_amdgcn_sqrtf(fmaxf(hacc, 0.0f));
                        float w    = __builtin_amdgcn_exp2f(dist * sc);
                        __half2 rg2 = pixh2[pb + j     ]; // R|G
                        __half2 by2 = pixh2[pb + j + 91]; // B|Y
                        aR[j] += w * __half2float(rg2.x); // -> v_fma_mix_f32
                        aG[j] += w * __half2float(rg2.y);
                        aB[j] += w * __half2float(by2.x);
                        aD[j] += w;
                    }
                }
                __syncthreads();
            }
            // ---- slide window by 3 rows for next group ----
            if (p1 && g < 6) {
                #pragma unroll
                for (int m = 18; m >= 3; --m) ys[m] = ys[m-3];
                #pragma unroll
                for (int m = 0; m < 3; ++m)
                    ys[m] = LDY(r0 + 5 + m - d, cs);
            }
        }
    }

    // ---------------- epilogue ----------------------------------------------
    const int gr = ty*TH + r;
    const int gc = tx*TW + c0;
    float* op = out + ibase + (size_t)gr*IMG + gc;
    #pragma unroll
    for (int j = 0; j < 8; ++j) {
        float iv = 1.0f / aD[j];
        op[j         ] = fminf(fmaxf(aR[j]*iv, 0.f), 1.f);
        op[j +     HW] = fminf(fmaxf(aG[j]*iv, 0.f), 1.f);
        op[j + 2 * HW] = fminf(fmaxf(aB[j]*iv, 0.f), 1.f);
    }
}

extern "C" void kernel_launch(void* const* d_in, const int* in_sizes, int n_in,
                              void* d_out, int out_size, void* d_ws, size_t ws_size,
                              hipStream_t stream) {
    const float* rgb = (const float*)d_in[0];
    const float* h   = (const float*)d_in[1];
    float* out       = (float*)d_out;
    dim3 grid(IMG/TW, IMG/TH, 8);   // 8 x 16 x 8 = 1024 blocks
    nlm_kernel<<<grid, 256, 0, stream>>>(rgb, h, out);
}

// Round 10
// 726.337 us; speedup vs baseline: 11.5034x; 1.1299x over previous
//
#include <hip/hip_runtime.h>
#include <hip/hip_fp16.h>

// Non-local means, 8x3x512x512 fp32, search 21x21 (R=10), patch 7x7 (PR=3),
// circular wrap (jnp.roll semantics).
//
// v7 = v6 math, restructured for occupancy + fewer barriers:
//   - 32x32 tile: LDS 38116 B -> 4 blocks/CU; grid 2048 = 8/CU, zero tail
//   - dy processed in PAIRS into two vert buffers (vertA=dy, vertB=dy+1):
//     one barrier pair per 2 shifts (462 vs 882), 2x ILP between barriers
//   - all bank patterns enumerated ~2-way (free)

#define IMG   512
#define HW    (IMG*IMG)
#define TW    32
#define TH    32
#define RWIN  10
#define HALO  13
#define PROWS 59             // staged rows 0..58
#define PCOLS 59             // staged cols 0..58
#define PSTR  119            // half2 words/row: [0,58]=R|G [59,117]=B|Y [118] pad
#define BYOFF 59
#define VCOLS 38             // vert col slots (tile cols -3..34)
#define VTSTR 33             // vert_t[col][row], rows 0..32 (32 junk)

// Y (f16) is the hi half of the B|Y word
#define LDY(row, col) __half2float(pixh2[(row)*PSTR + BYOFF + (col)].y)

__launch_bounds__(256, 4)
__global__ void nlm_kernel(const float* __restrict__ rgb,
                           const float* __restrict__ hptr,
                           float* __restrict__ out)
{
    __shared__ __half2 pixh2[PROWS * PSTR];     // 28084 B
    __shared__ float   vertA[VCOLS * VTSTR];    //  5016 B
    __shared__ float   vertB[VCOLS * VTSTR];    //  5016 B  (38116 B -> 4 blk/CU)

    const int tid = threadIdx.x;
    const int tx  = blockIdx.x;   // 0..15
    const int ty  = blockIdx.y;   // 0..15
    const int b   = blockIdx.z;   // 0..7

    const float hval  = hptr[0];
    const float inv_h = 1.0f / (fmaxf(hval, 0.0f) + 1e-8f);
    const float sc    = -inv_h * 1.4426950408889634f;   // exp2 scale

    // ---------------- stage packed RGBY (f16) -------------------------------
    const size_t ibase = (size_t)b * 3 * HW;
    const int row0 = ty*TH - HALO;
    const int col0 = tx*TW - HALO;
    for (int i = tid; i < PROWS*PCOLS; i += 256) {
        int rr = i / PCOLS;
        int cc = i - rr*PCOLS;
        int gr = (row0 + rr) & (IMG-1);
        int gc = (col0 + cc) & (IMG-1);
        size_t g = ibase + (size_t)gr*IMG + gc;
        float R  = fminf(fmaxf(rgb[g         ], 0.f), 1.f);
        float G  = fminf(fmaxf(rgb[g +     HW], 0.f), 1.f);
        float Bv = fminf(fmaxf(rgb[g + 2 * HW], 0.f), 1.f);
        float Y  = 0.299f*R + 0.587f*G + 0.114f*Bv;
        int o = rr*PSTR + cc;
        pixh2[o        ] = __floats2half2_rn(R, G);
        pixh2[o + BYOFF] = __floats2half2_rn(Bv, Y);
    }
    __syncthreads();

    // ---------------- phase-1 statics: 114 column strips (38 x 3) -----------
    const int  c  = tid % VCOLS;      // vert col slot (tile col c-3)
    const int  rg = tid / VCOLS;      // 0..2 (valid when tid<114)
    const int  r0 = rg * 11;          // vert rows r0..r0+10 (rg=2 row 32 junk)
    const bool p1 = tid < 114;
    float yown[17];
    if (p1) {
        #pragma unroll
        for (int k = 0; k < 17; ++k)
            yown[k] = LDY(r0 + 10 + k, c + 10);
    }

    // ---------------- phase-2 statics ---------------------------------------
    const int r   = tid >> 3;         // 0..31
    const int c0  = (tid & 7) * 4;    // 0..28
    const int vb2 = c0*VTSTR + r;     // vv[k] = vert[(c0+k)*VTSTR + r]

    float aR[4], aG[4], aB[4], aD[4];
    #pragma unroll
    for (int j = 0; j < 4; ++j) { aR[j]=0.f; aG[j]=0.f; aB[j]=0.f; aD[j]=0.f; }

    // ---------------- shift loop: dx outer, dy in pairs ---------------------
    #pragma unroll 1
    for (int dx = -RWIN; dx <= RWIN; ++dx) {
        const int cs = c + 10 - dx;               // shifted y column (0..57)
        // window: ys[m] = LDY(r0 + 9 - d + m, cs) for current pair base d
        float ys[18];
        if (p1) {
            #pragma unroll
            for (int m = 0; m < 18; ++m)
                ys[m] = LDY(r0 + 19 + m, cs);     // d = -10
        }
        #pragma unroll 1
        for (int p = 0; p < 10; ++p) {
            const int d = -RWIN + 2*p;            // pair (d, d+1)
            // ---- phase 1: two vertical 7-box passes ----
            if (p1) {
                float tA[17], tB[17];
                #pragma unroll
                for (int k = 0; k < 17; ++k) {
                    tA[k] = yown[k] - ys[k+1];    // dy = d
                    tB[k] = yown[k] - ys[k];      // dy = d+1
                }
                float vA = tA[0]*tA[0], vB = tB[0]*tB[0];
                #pragma unroll
                for (int k = 1; k < 7; ++k) {
                    vA = fmaf(tA[k], tA[k], vA);
                    vB = fmaf(tB[k], tB[k], vB);
                }
                float* vpA = &vertA[c*VTSTR + r0];
                float* vpB = &vertB[c*VTSTR + r0];
                vpA[0] = vA; vpB[0] = vB;
                #pragma unroll
                for (int j = 1; j < 11; ++j) {
                    vA = fmaf(tA[j+6]-tA[j-1], tA[j+6]+tA[j-1], vA);
                    vB = fmaf(tB[j+6]-tB[j-1], tB[j+6]+tB[j-1], vB);
                    vpA[j] = vA; vpB[j] = vB;
                }
            }
            __syncthreads();
            // ---- phase 2: both dys ----
            {
                float vvA[10], vvB[10];
                #pragma unroll
                for (int k = 0; k < 10; ++k) {
                    vvA[k] = vertA[vb2 + k*VTSTR];
                    vvB[k] = vertB[vb2 + k*VTSTR];
                }
                float haccA = vvA[0]+vvA[1]+vvA[2]+vvA[3]+vvA[4]+vvA[5]+vvA[6];
                float haccB = vvB[0]+vvB[1]+vvB[2]+vvB[3]+vvB[4]+vvB[5]+vvB[6];
                const int prowA = r - d + HALO;           // dy=d
                const int pbA   = prowA*PSTR + (c0 - dx + HALO);
                const int pbB   = pbA - PSTR;             // dy=d+1 row
                #pragma unroll
                for (int j = 0; j < 4; ++j) {
                    if (j) {
                        haccA += vvA[j+6] - vvA[j-1];
                        haccB += vvB[j+6] - vvB[j-1];
                    }
                    float wA = __builtin_amdgcn_exp2f(
                        __builtin_amdgcn_sqrtf(fmaxf(haccA, 0.0f)) * sc);
                    float wB = __builtin_amdgcn_exp2f(
                        __builtin_amdgcn_sqrtf(fmaxf(haccB, 0.0f)) * sc);
                    __half2 rgA = pixh2[pbA + j], byA = pixh2[pbA + BYOFF + j];
                    __half2 rgB = pixh2[pbB + j], byB = pixh2[pbB + BYOFF + j];
                    aR[j] += wA * __half2float(rgA.x);    // v_fma_mix
                    aR[j] += wB * __half2float(rgB.x);
                    aG[j] += wA * __half2float(rgA.y);
                    aG[j] += wB * __half2float(rgB.y);
                    aB[j] += wA * __half2float(byA.x);
                    aB[j] += wB * __half2float(byB.x);
                    aD[j] += wA + wB;
                }
            }
            __syncthreads();
            // ---- slide window for next round ----
            if (p1) {
                if (p < 9) {          // next pair base d+2
                    #pragma unroll
                    for (int m = 17; m >= 2; --m) ys[m] = ys[m-2];
                    ys[0] = LDY(r0 + 7 - d, cs);
                    ys[1] = LDY(r0 + 8 - d, cs);
                } else {              // final single dy=+10 (window d'=9)
                    #pragma unroll
                    for (int m = 17; m >= 1; --m) ys[m] = ys[m-1];
                    ys[0] = LDY(r0, cs);
                }
            }
        }
        // ---- single dy = +10 round ----
        if (p1) {
            float tA[17];
            #pragma unroll
            for (int k = 0; k < 17; ++k) tA[k] = yown[k] - ys[k];
            float vA = tA[0]*tA[0];
            #pragma unroll
            for (int k = 1; k < 7; ++k) vA = fmaf(tA[k], tA[k], vA);
            float* vpA = &vertA[c*VTSTR + r0];
            vpA[0] = vA;
            #pragma unroll
            for (int j = 1; j < 11; ++j) {
                vA = fmaf(tA[j+6]-tA[j-1], tA[j+6]+tA[j-1], vA);
                vpA[j] = vA;
            }
        }
        __syncthreads();
        {
            float vvA[10];
            #pragma unroll
            for (int k = 0; k < 10; ++k) vvA[k] = vertA[vb2 + k*VTSTR];
            float haccA = vvA[0]+vvA[1]+vvA[2]+vvA[3]+vvA[4]+vvA[5]+vvA[6];
            const int prowA = r + 3;                      // r - 10 + HALO
            const int pbA   = prowA*PSTR + (c0 - dx + HALO);
            #pragma unroll
            for (int j = 0; j < 4; ++j) {
                if (j) haccA += vvA[j+6] - vvA[j-1];
                float wA = __builtin_amdgcn_exp2f(
                    __builtin_amdgcn_sqrtf(fmaxf(haccA, 0.0f)) * sc);
                __half2 rgA = pixh2[pbA + j], byA = pixh2[pbA + BYOFF + j];
                aR[j] += wA * __half2float(rgA.x);
                aG[j] += wA * __half2float(rgA.y);
                aB[j] += wA * __half2float(byA.x);
                aD[j] += wA;
            }
        }
        __syncthreads();
    }

    // ---------------- epilogue ----------------------------------------------
    const int gr = ty*TH + r;
    const int gc = tx*TW + c0;
    float* op = out + ibase + (size_t)gr*IMG + gc;
    #pragma unroll
    for (int j = 0; j < 4; ++j) {
        float iv = 1.0f / aD[j];
        op[j         ] = fminf(fmaxf(aR[j]*iv, 0.f), 1.f);
        op[j +     HW] = fminf(fmaxf(aG[j]*iv, 0.f), 1.f);
        op[j + 2 * HW] = fminf(fmaxf(aB[j]*iv, 0.f), 1.f);
    }
}

extern "C" void kernel_launch(void* const* d_in, const int* in_sizes, int n_in,
                              void* d_out, int out_size, void* d_ws, size_t ws_size,
                              hipStream_t stream) {
    const float* rgb = (const float*)d_in[0];
    const float* h   = (const float*)d_in[1];
    float* out       = (float*)d_out;
    dim3 grid(IMG/TW, IMG/TH, 8);   // 16 x 16 x 8 = 2048 blocks
    nlm_kernel<<<grid, 256, 0, stream>>>(rgb, h, out);
}